// Round 4
// baseline (349.879 us; speedup 1.0000x reference)
//
#include <hip/hip_runtime.h>
#include <math.h>

#define EMBED    256
#define HIDDEN   512
#define KDIM     512
#define Nn       2000
#define Ee       2000
#define BMT      64      // edges per tile
#define TPB      16      // tiles per block
#define NBLK     250     // 250 * 16 * 64 = 256000 edges
#define NTHREADS 512     // 8 waves
#define PITCH    520     // shorts per feat row (512 + 8 pad)

typedef __attribute__((ext_vector_type(8)))  short bf16x8;
typedef __attribute__((ext_vector_type(16))) float f32x16;

static __device__ __forceinline__ short f2bf(float f) {
  unsigned u = __builtin_bit_cast(unsigned, f);
  u += 0x7fffu + ((u >> 16) & 1u);
  return (short)(u >> 16);
}

static __device__ __forceinline__ bf16x8 cvt8(float4 a, float4 b) {
  bf16x8 v;
  v[0]=f2bf(a.x); v[1]=f2bf(a.y); v[2]=f2bf(a.z); v[3]=f2bf(a.w);
  v[4]=f2bf(b.x); v[5]=f2bf(b.y); v[6]=f2bf(b.z); v[7]=f2bf(b.w);
  return v;
}

// ---- prep: W1 (513x512 f32 [k][n]) -> W1T bf16 [n][k], k<512 ----
__global__ void w1t_kernel(const float* __restrict__ W1, short* __restrict__ W1T) {
  __shared__ float t[32][33];
  const int kt = blockIdx.x & 15;
  const int nt = blockIdx.x >> 4;
  const int tx = threadIdx.x & 31;
  const int ty = threadIdx.x >> 5;
#pragma unroll
  for (int r = 0; r < 32; r += 8)
    t[ty + r][tx] = W1[(kt * 32 + ty + r) * HIDDEN + nt * 32 + tx];
  __syncthreads();
#pragma unroll
  for (int r = 0; r < 32; r += 8)
    W1T[(nt * 32 + ty + r) * KDIM + kt * 32 + tx] = f2bf(t[tx][ty + r]);
}

// ---- main fused kernel: 250 blocks x 16 tiles of 64 edges, one barrier/tile ----
__global__ __launch_bounds__(NTHREADS, 2)
void edge_kernel(const float* __restrict__ emb, const float* __restrict__ locs,
                 const int* __restrict__ edges, const int* __restrict__ dbias,
                 const float* __restrict__ W1, const float* __restrict__ b1,
                 const float* __restrict__ W2, const float* __restrict__ b2,
                 const short* __restrict__ W1T, float* __restrict__ out)
{
  __shared__ short  feat[2][BMT][PITCH];   // 133,120 B
  __shared__ float4 ep_s[HIDDEN];          //   8,192 B  {b1, W1[512][n], W2, 0}
  __shared__ float  part_s[2][8][BMT];     //   4,096 B
  __shared__ float  dist_s[2][BMT];        //     512 B
  __shared__ int    valid_s[2][BMT];       //     512 B   (total 146,432 B)

  const int tid = threadIdx.x;

  // bijective XCD-chunked swizzle over 250 blocks (xcd 0,1 -> 32 chunks; 2..7 -> 31)
  const int orig = blockIdx.x;
  const int xcd  = orig & 7;
  const int idx  = orig >> 3;
  const int sbid = (xcd < 2 ? xcd * 32 : 64 + (xcd - 2) * 31) + idx;
  const int edge0 = sbid * (TPB * BMT);

  ep_s[tid] = make_float4(b1[tid], W1[(size_t)KDIM * HIDDEN + tid], W2[tid], 0.f);

  // gather mapping: thread -> (edge e, half hlf in {i,j}, 64-float part prt)
  const int e   = tid >> 3;
  const int hlf = (tid >> 2) & 1;
  const int prt = tid & 3;

  const int lane = tid & 63;
  const int wv   = tid >> 6;
  const int ln31 = lane & 31;
  const int kg   = lane >> 5;

  const short* pA0 = W1T + (size_t)(wv * 64 + ln31) * KDIM + kg * 8;
  const short* pA1 = pA0 + 32 * (size_t)KDIM;

  const float b2s_base = b2[0] + (float)dbias[0];

  auto do_meta = [&](int tl, int mb) {
    const int g  = edge0 + tl * BMT + tid;
    const int b  = g / Ee;
    const int i0 = edges[2 * g];
    const int j0 = edges[2 * g + 1];
    valid_s[mb][tid] = (i0 >= 0) && (j0 >= 0);
    const int ib = b * Nn + (i0 < 0 ? 0 : i0);
    const int jb = b * Nn + (j0 < 0 ? 0 : j0);
    const float dx = locs[2 * (size_t)ib]     - locs[2 * (size_t)jb];
    const float dy = locs[2 * (size_t)ib + 1] - locs[2 * (size_t)jb + 1];
    dist_s[mb][tid] = sqrtf(dx * dx + dy * dy);
  };

  auto rowptr = [&](int tl) -> const float* {
    const int g = edge0 + tl * BMT + e;
    const int b = g / Ee;
    const int v = edges[2 * g + hlf];
    const int r = b * Nn + (v < 0 ? 0 : v);
    return emb + (size_t)r * EMBED + prt * 64;
  };

  // the ONE packing routine: 32 floats (8x float4) -> 32 bf16 shorts at dst
  auto pack_store = [&](const float4 (&g)[8], short* dst) {
#pragma unroll
    for (int h = 0; h < 4; ++h)
      *(bf16x8*)(dst + h * 8) = cvt8(g[2 * h], g[2 * h + 1]);
  };

  // ---- prologue: tile 0 meta + full gather + stage ----
  if (tid < BMT) do_meta(0, 0);
  {
    const float* p = rowptr(0);
    short* dst = &feat[0][e][hlf * 256 + prt * 64];
    float4 g[8];
#pragma unroll
    for (int q = 0; q < 8; ++q) g[q] = *(const float4*)(p + 4 * q);
    pack_store(g, dst);
#pragma unroll
    for (int q = 0; q < 8; ++q) g[q] = *(const float4*)(p + 32 + 4 * q);
    pack_store(g, dst + 32);
  }
  __syncthreads();

  // ---- tile loop: ONE barrier per tile ----
#pragma unroll 1
  for (int tt = 0; tt < TPB; ++tt) {
    const int bb = tt & 1;
    const int nb = bb ^ 1;
    const bool more = (tt < TPB - 1);

    // issue gather group A for tile tt+1 (held in regs; landed at k==10)
    float4 ga[8], gb[8];
    const float* gp = more ? rowptr(tt + 1) : (const float*)emb;
    if (more) {
#pragma unroll
      for (int q = 0; q < 8; ++q) ga[q] = *(const float4*)(gp + 4 * q);
    }

    // wave 0: store tile tt-1 logits (part_s[nb] written before last barrier),
    // then meta for tile tt+1
    if (tid < BMT) {
      if (tt > 0) {
        float s = 0.f;
#pragma unroll
        for (int w = 0; w < 8; ++w) s += part_s[nb][w][tid];
        float logit = s + b2s_base;
        if (!valid_s[nb][tid]) logit = -__builtin_inff();
        out[edge0 + (tt - 1) * BMT + tid] = logit;
      }
      if (more) do_meta(tt + 1, nb);
    }

    f32x16 acc[2][2];
#pragma unroll
    for (int et = 0; et < 2; ++et)
#pragma unroll
      for (int nt = 0; nt < 2; ++nt)
#pragma unroll
        for (int q = 0; q < 16; ++q) acc[et][nt][q] = 0.f;

    short* dstn = &feat[nb][e][hlf * 256 + prt * 64];

#pragma unroll
    for (int k = 0; k < 32; ++k) {
      bf16x8 wa0 = *(const bf16x8*)(pA0 + k * 16);
      bf16x8 wa1 = *(const bf16x8*)(pA1 + k * 16);
      bf16x8 fb0 = *(const bf16x8*)(&feat[bb][ln31][k * 16 + kg * 8]);
      bf16x8 fb1 = *(const bf16x8*)(&feat[bb][32 + ln31][k * 16 + kg * 8]);
      acc[0][0] = __builtin_amdgcn_mfma_f32_32x32x16_bf16(wa0, fb0, acc[0][0], 0, 0, 0);
      acc[0][1] = __builtin_amdgcn_mfma_f32_32x32x16_bf16(wa1, fb0, acc[0][1], 0, 0, 0);
      acc[1][0] = __builtin_amdgcn_mfma_f32_32x32x16_bf16(wa0, fb1, acc[1][0], 0, 0, 0);
      acc[1][1] = __builtin_amdgcn_mfma_f32_32x32x16_bf16(wa1, fb1, acc[1][1], 0, 0, 0);

      if (k == 10 && more) {
        pack_store(ga, dstn);                  // land A into next buffer
#pragma unroll
        for (int q = 0; q < 8; ++q) gb[q] = *(const float4*)(gp + 32 + 4 * q);
      }
      if (k == 22 && more) {
        pack_store(gb, dstn + 32);             // land B
      }
    }

    // epilogue: dist col + bias + relu + in-lane dot with W2
    const float d0 = dist_s[bb][ln31];
    const float d1 = dist_s[bb][32 + ln31];
    float ps0 = 0.f, ps1 = 0.f;
#pragma unroll
    for (int nt = 0; nt < 2; ++nt) {
#pragma unroll
      for (int r = 0; r < 16; ++r) {
        const int n = wv * 64 + nt * 32 + (r & 3) + ((r >> 2) << 3) + (kg << 2);
        const float4 ep = ep_s[n];
        float p0 = acc[0][nt][r] + ep.x + d0 * ep.y;
        float p1 = acc[1][nt][r] + ep.x + d1 * ep.y;
        ps0 += fmaxf(p0, 0.f) * ep.z;
        ps1 += fmaxf(p1, 0.f) * ep.z;
      }
    }
    ps0 += __shfl_xor(ps0, 32, 64);
    ps1 += __shfl_xor(ps1, 32, 64);
    if (lane < 32) {
      part_s[bb][wv][ln31]      = ps0;
      part_s[bb][wv][32 + ln31] = ps1;
    }
    __syncthreads();
  }

  // final tile store
  if (tid < BMT) {
    const int pb = (TPB - 1) & 1;
    float s = 0.f;
#pragma unroll
    for (int w = 0; w < 8; ++w) s += part_s[pb][w][tid];
    float logit = s + b2s_base;
    if (!valid_s[pb][tid]) logit = -__builtin_inff();
    out[edge0 + (TPB - 1) * BMT + tid] = logit;
  }
}

extern "C" void kernel_launch(void* const* d_in, const int* in_sizes, int n_in,
                              void* d_out, int out_size, void* d_ws, size_t ws_size,
                              hipStream_t stream) {
  const float* emb   = (const float*)d_in[0];
  const float* locs  = (const float*)d_in[1];
  const int*   edges = (const int*)d_in[2];
  const int*   dbias = (const int*)d_in[3];
  const float* W1    = (const float*)d_in[4];
  const float* b1    = (const float*)d_in[5];
  const float* W2    = (const float*)d_in[6];
  const float* b2    = (const float*)d_in[7];
  float*       out   = (float*)d_out;
  short*       W1T   = (short*)d_ws;   // 512*512*2 = 512 KiB

  w1t_kernel<<<dim3(256), dim3(256), 0, stream>>>(W1, W1T);
  edge_kernel<<<dim3(NBLK), dim3(NTHREADS), 0, stream>>>(
      emb, locs, edges, dbias, W1, b1, W2, b2, (const short*)W1T, out);
}

// Round 5
// 222.833 us; speedup vs baseline: 1.5701x; 1.5701x over previous
//
#include <hip/hip_runtime.h>
#include <math.h>

#define EMBED    256
#define HIDDEN   512
#define KDIM     512
#define Nn       2000
#define Ee       2000
#define BM       128     // edges per block
#define NTHREADS 1024    // 16 waves = 4 edge-groups x 4 n-groups
#define NBLK     2000    // 2000 * 128 = 256000 edges
#define PITCH    72      // shorts per feat row (64 + 8 pad; measured 0-conflict)

typedef __attribute__((ext_vector_type(8)))  short bf16x8;
typedef __attribute__((ext_vector_type(16))) float f32x16;

static __device__ __forceinline__ short f2bf(float f) {
  unsigned u = __builtin_bit_cast(unsigned, f);
  u += 0x7fffu + ((u >> 16) & 1u);
  return (short)(u >> 16);
}

static __device__ __forceinline__ bf16x8 cvt8(float4 a, float4 b) {
  bf16x8 v;
  v[0]=f2bf(a.x); v[1]=f2bf(a.y); v[2]=f2bf(a.z); v[3]=f2bf(a.w);
  v[4]=f2bf(b.x); v[5]=f2bf(b.y); v[6]=f2bf(b.z); v[7]=f2bf(b.w);
  return v;
}

// ---- prep: W1 (513x512 f32 [k][n]) -> fragment-major W1F ----
// W1F[((tn*32 + tk)*64 + lane)*8 + q] = W1[tk*16 + (lane>>5)*8 + q][tn*32 + (lane&31)]
// so each wave's A-fragment load in the main kernel is base + lane*16B (coalesced).
__global__ void w1f_kernel(const float* __restrict__ W1, short* __restrict__ W1F) {
  const int t  = blockIdx.x * 512 + threadIdx.x;   // 32768 fragment-lanes
  const int l  = t & 63;
  const int tk = (t >> 6) & 31;
  const int tn = t >> 11;
  const int n  = tn * 32 + (l & 31);
  const int k0 = tk * 16 + (l >> 5) * 8;
  bf16x8 v;
#pragma unroll
  for (int q = 0; q < 8; ++q)
    v[q] = f2bf(W1[(size_t)(k0 + q) * HIDDEN + n]);
  *(bf16x8*)(W1F + (size_t)t * 8) = v;
}

// ---- main fused kernel: 2000 blocks x 128 edges, 16 waves ----
__global__ __launch_bounds__(NTHREADS, 4)
void edge_kernel(const float* __restrict__ emb, const float* __restrict__ locs,
                 const int* __restrict__ edges, const int* __restrict__ dbias,
                 const float* __restrict__ W1, const float* __restrict__ b1,
                 const float* __restrict__ W2, const float* __restrict__ b2,
                 const short* __restrict__ W1F, float* __restrict__ out)
{
  __shared__ short  feat[2][BM][PITCH];   // 36,864 B (per-64K-chunk feats, dbuf)
  __shared__ float4 ep_s[HIDDEN];         //  8,192 B {b1, W1[512][n], W2, 0}
  __shared__ float  part_s[4][BM];        //  2,048 B
  __shared__ float  dist_s[BM];
  __shared__ int    valid_s[BM];
  __shared__ int    ibase_s[BM];
  __shared__ int    jbase_s[BM];          // total ~49 KB

  const int tid = threadIdx.x;

  // bijective XCD-chunked swizzle: 2000 = 8 * 250
  const int wg = (blockIdx.x & 7) * (NBLK / 8) + (blockIdx.x >> 3);

  // ---- meta + epilogue tables ----
  if (tid < BM) {
    const int g  = wg * BM + tid;
    const int b  = g / Ee;
    const int i0 = edges[2 * g];
    const int j0 = edges[2 * g + 1];
    valid_s[tid] = (i0 >= 0) && (j0 >= 0);
    const int ib = b * Nn + (i0 < 0 ? 0 : i0);
    const int jb = b * Nn + (j0 < 0 ? 0 : j0);
    ibase_s[tid] = ib;
    jbase_s[tid] = jb;
    const float dx = locs[2 * (size_t)ib]     - locs[2 * (size_t)jb];
    const float dy = locs[2 * (size_t)ib + 1] - locs[2 * (size_t)jb + 1];
    dist_s[tid] = sqrtf(dx * dx + dy * dy);
  }
  if (tid < HIDDEN)
    ep_s[tid] = make_float4(b1[tid], W1[(size_t)KDIM * HIDDEN + tid], W2[tid], 0.f);
  __syncthreads();

  // gather mapping: 8 threads per edge, 32 B (8 floats) each per chunk
  const int e  = tid >> 3;     // edge 0..127
  const int sq = tid & 7;

  const int lane = tid & 63;
  const int wv   = tid >> 6;   // 0..15
  const int eg   = wv & 3;     // edge-group: edges [eg*32, +32)
  const int ng   = wv >> 2;    // n-group:   hidden [ng*128, +128)
  const int ln31 = lane & 31;
  const int kg   = lane >> 5;

  // ---- prologue: stage chunk 0 (emb_i, k 0..63) ----
  {
    const float* p = emb + (size_t)ibase_s[e] * EMBED + sq * 8;
    float4 v0 = *(const float4*)(p);
    float4 v1 = *(const float4*)(p + 4);
    *(bf16x8*)&feat[0][e][sq * 8] = cvt8(v0, v1);
  }
  __syncthreads();

  f32x16 acc[4];               // n-tiles nt=0..3 of wave's 128-n slice
#pragma unroll
  for (int nt = 0; nt < 4; ++nt)
#pragma unroll
    for (int q = 0; q < 16; ++q) acc[nt][q] = 0.f;

  // ---- K loop: 8 chunks of 64 (i embeds: c 0..3, j embeds: c 4..7) ----
#pragma unroll 1
  for (int c = 0; c < 8; ++c) {
    const int bb = c & 1;
    const int nb = bb ^ 1;

    // T14 issue-early: gather chunk c+1 into regs (8 VGPRs held)
    float4 g0, g1;
    if (c < 7) {
      const int cc = c + 1;
      const int rb = (cc < 4) ? ibase_s[e] : jbase_s[e];
      const float* p = emb + (size_t)rb * EMBED + (cc & 3) * 64 + sq * 8;
      g0 = *(const float4*)(p);
      g1 = *(const float4*)(p + 4);
    }

    // MFMA on current buffer; W1F fragment loads are lane-coalesced streams
    const short* wbase = W1F + ((size_t)(ng * 4) * 32 + c * 4) * 64 * 8 + lane * 8;
#pragma unroll
    for (int ks = 0; ks < 4; ++ks) {
      bf16x8 fb = *(const bf16x8*)(&feat[bb][eg * 32 + ln31][ks * 16 + kg * 8]);
#pragma unroll
      for (int nt = 0; nt < 4; ++nt) {
        bf16x8 wa = *(const bf16x8*)(wbase + ((size_t)(nt * 32 + ks) * 64) * 8);
        acc[nt] = __builtin_amdgcn_mfma_f32_32x32x16_bf16(wa, fb, acc[nt], 0, 0, 0);
      }
    }

    // T14 write-late: land gather into next buffer
    if (c < 7)
      *(bf16x8*)&feat[nb][e][sq * 8] = cvt8(g0, g1);
    __syncthreads();
  }

  // ---- epilogue: dist col + bias + relu + in-lane W2 dot over wave's n ----
  const float d = dist_s[eg * 32 + ln31];
  float ps = 0.f;
#pragma unroll
  for (int nt = 0; nt < 4; ++nt) {
#pragma unroll
    for (int r = 0; r < 16; ++r) {
      const int n = ng * 128 + nt * 32 + (r & 3) + ((r >> 2) << 3) + (kg << 2);
      const float4 ep = ep_s[n];
      float p = acc[nt][r] + ep.x + d * ep.y;
      ps += fmaxf(p, 0.f) * ep.z;
    }
  }
  ps += __shfl_xor(ps, 32, 64);          // fold kg halves (rows +4)
  if (lane < 32) part_s[ng][eg * 32 + ln31] = ps;
  __syncthreads();

  if (tid < BM) {
    float s = part_s[0][tid] + part_s[1][tid] + part_s[2][tid] + part_s[3][tid];
    float logit = s + b2[0] + (float)dbias[0];
    if (!valid_s[tid]) logit = -__builtin_inff();
    out[(size_t)wg * BM + tid] = logit;
  }
}

extern "C" void kernel_launch(void* const* d_in, const int* in_sizes, int n_in,
                              void* d_out, int out_size, void* d_ws, size_t ws_size,
                              hipStream_t stream) {
  const float* emb   = (const float*)d_in[0];
  const float* locs  = (const float*)d_in[1];
  const int*   edges = (const int*)d_in[2];
  const int*   dbias = (const int*)d_in[3];
  const float* W1    = (const float*)d_in[4];
  const float* b1    = (const float*)d_in[5];
  const float* W2    = (const float*)d_in[6];
  const float* b2    = (const float*)d_in[7];
  float*       out   = (float*)d_out;
  short*       W1F   = (short*)d_ws;   // 512*512*2 = 512 KiB fragment-major

  w1f_kernel<<<dim3(64), dim3(512), 0, stream>>>(W1, W1F);
  edge_kernel<<<dim3(NBLK), dim3(NTHREADS), 0, stream>>>(
      emb, locs, edges, dbias, W1, b1, W2, b2, (const short*)W1F, out);
}

// Round 6
// 164.681 us; speedup vs baseline: 2.1246x; 1.3531x over previous
//
#include <hip/hip_runtime.h>
#include <math.h>

#define EMBED    256
#define HIDDEN   512
#define KDIM     512
#define Nn       2000
#define Ee       2000
#define BM       64      // edges per block
#define NTHREADS 512     // 8 waves, each owns a 64-wide n-slice
#define NBLK     4000    // 4000 * 64 = 256000 edges
#define PITCH    72      // shorts per feat row (64 + 8 pad; conflict-free b128)

typedef __attribute__((ext_vector_type(8)))  short bf16x8;
typedef __attribute__((ext_vector_type(16))) float f32x16;

static __device__ __forceinline__ short f2bf(float f) {
  unsigned u = __builtin_bit_cast(unsigned, f);
  u += 0x7fffu + ((u >> 16) & 1u);
  return (short)(u >> 16);
}

static __device__ __forceinline__ bf16x8 cvt8(float4 a, float4 b) {
  bf16x8 v;
  v[0]=f2bf(a.x); v[1]=f2bf(a.y); v[2]=f2bf(a.z); v[3]=f2bf(a.w);
  v[4]=f2bf(b.x); v[5]=f2bf(b.y); v[6]=f2bf(b.z); v[7]=f2bf(b.w);
  return v;
}

// ---- prep: W1 (513x512 f32 [k][n]) -> fragment-major W1F bf16 ----
// W1F[((tn*32 + tk)*64 + lane)*8 + q] = W1[tk*16 + (lane>>5)*8 + q][tn*32 + (lane&31)]
__global__ void w1f_kernel(const float* __restrict__ W1, short* __restrict__ W1F) {
  const int t  = blockIdx.x * 512 + threadIdx.x;   // 32768 fragment-lanes
  const int l  = t & 63;
  const int tk = (t >> 6) & 31;
  const int tn = t >> 11;
  const int n  = tn * 32 + (l & 31);
  const int k0 = tk * 16 + (l >> 5) * 8;
  bf16x8 v;
#pragma unroll
  for (int q = 0; q < 8; ++q)
    v[q] = f2bf(W1[(size_t)(k0 + q) * HIDDEN + n]);
  *(bf16x8*)(W1F + (size_t)t * 8) = v;
}

// ---- main fused kernel: 4000 blocks x 64 edges, 8 waves ----
__global__ __launch_bounds__(NTHREADS, 4)
void edge_kernel(const float* __restrict__ emb, const float* __restrict__ locs,
                 const int* __restrict__ edges, const int* __restrict__ dbias,
                 const float* __restrict__ W1, const float* __restrict__ b1,
                 const float* __restrict__ W2, const float* __restrict__ b2,
                 const short* __restrict__ W1F, float* __restrict__ out)
{
  __shared__ short  feat[2][BM][PITCH];   // 18,432 B (dbuf 64-K chunks)
  __shared__ float4 ep_s[HIDDEN];         //  8,192 B {b1, W1[512][n], W2, 0}
  __shared__ float  part_s[8][BM];        //  2,048 B
  __shared__ float  dist_s[BM];
  __shared__ int    valid_s[BM];
  __shared__ int    ibase_s[BM];
  __shared__ int    jbase_s[BM];          // total ~29.7 KB -> 2 blocks/CU

  const int tid = threadIdx.x;

  // bijective XCD-chunked swizzle: 4000 = 8 * 500
  const int wg = (blockIdx.x & 7) * (NBLK / 8) + (blockIdx.x >> 3);

  // ---- meta + epilogue tables ----
  if (tid < BM) {
    const int g  = wg * BM + tid;
    const int b  = g / Ee;
    const int i0 = edges[2 * g];
    const int j0 = edges[2 * g + 1];
    valid_s[tid] = (i0 >= 0) && (j0 >= 0);
    const int ib = b * Nn + (i0 < 0 ? 0 : i0);
    const int jb = b * Nn + (j0 < 0 ? 0 : j0);
    ibase_s[tid] = ib;
    jbase_s[tid] = jb;
    const float dx = locs[2 * (size_t)ib]     - locs[2 * (size_t)jb];
    const float dy = locs[2 * (size_t)ib + 1] - locs[2 * (size_t)jb + 1];
    dist_s[tid] = sqrtf(dx * dx + dy * dy);
  }
  ep_s[tid] = make_float4(b1[tid], W1[(size_t)KDIM * HIDDEN + tid], W2[tid], 0.f);
  asm volatile("s_waitcnt lgkmcnt(0)" ::: "memory");
  __builtin_amdgcn_s_barrier();
  asm volatile("" ::: "memory");

  // staging: 8 threads per edge, 32 B (8 floats) per chunk
  const int e  = tid >> 3;     // edge 0..63
  const int sq = tid & 7;

  const int lane = tid & 63;
  const int ng   = tid >> 6;   // wave id 0..7 -> n-slice [ng*64, +64)
  const int ln31 = lane & 31;
  const int kg   = lane >> 5;

  // ---- prologue: stage chunk 0, then issue gather for chunk 1 (held) ----
  {
    const float* p = emb + (size_t)ibase_s[e] * EMBED + sq * 8;
    float4 v0 = *(const float4*)(p);
    float4 v1 = *(const float4*)(p + 4);
    *(bf16x8*)&feat[0][e][sq * 8] = cvt8(v0, v1);
  }
  float4 gh0, gh1;
  {
    const float* p = emb + (size_t)ibase_s[e] * EMBED + 64 + sq * 8;
    gh0 = *(const float4*)(p);
    gh1 = *(const float4*)(p + 4);
  }
  asm volatile("s_waitcnt lgkmcnt(0)" ::: "memory");
  __builtin_amdgcn_s_barrier();
  asm volatile("" ::: "memory");

  f32x16 acc[2][2];            // [edge-tile et][n-tile nt]
#pragma unroll
  for (int et = 0; et < 2; ++et)
#pragma unroll
    for (int nt = 0; nt < 2; ++nt)
#pragma unroll
      for (int q = 0; q < 16; ++q) acc[et][nt][q] = 0.f;

  // ---- K loop: 8 chunks of 64 ----
#pragma unroll 1
  for (int c = 0; c < 8; ++c) {
    const int bb = c & 1;
    const int nb = bb ^ 1;

    // wa fragment loads (L2, lane-coalesced) + MFMA
    const short* wb = W1F + ((size_t)(ng * 2) * 32 + c * 4) * 512 + lane * 8;
    bf16x8 wa0[4], wa1[4];
#pragma unroll
    for (int ks = 0; ks < 4; ++ks) {
      wa0[ks] = *(const bf16x8*)(wb + ks * 512);
      wa1[ks] = *(const bf16x8*)(wb + 32 * 512 + ks * 512);
    }
#pragma unroll
    for (int ks = 0; ks < 4; ++ks) {
      bf16x8 fb0 = *(const bf16x8*)(&feat[bb][ln31][ks * 16 + kg * 8]);
      bf16x8 fb1 = *(const bf16x8*)(&feat[bb][32 + ln31][ks * 16 + kg * 8]);
      acc[0][0] = __builtin_amdgcn_mfma_f32_32x32x16_bf16(wa0[ks], fb0, acc[0][0], 0, 0, 0);
      acc[0][1] = __builtin_amdgcn_mfma_f32_32x32x16_bf16(wa1[ks], fb0, acc[0][1], 0, 0, 0);
      acc[1][0] = __builtin_amdgcn_mfma_f32_32x32x16_bf16(wa0[ks], fb1, acc[1][0], 0, 0, 0);
      acc[1][1] = __builtin_amdgcn_mfma_f32_32x32x16_bf16(wa1[ks], fb1, acc[1][1], 0, 0, 0);
    }

    // land held gather (chunk c+1) into next buffer (ds_write; lgkm only)
    if (c < 7)
      *(bf16x8*)&feat[nb][e][sq * 8] = cvt8(gh0, gh1);

    // issue gather for chunk c+2 LAST (newest vmem -> counted waits spare it;
    // it stays in flight across the raw barrier, ~1.5 chunks until use)
    __builtin_amdgcn_sched_barrier(0);
    if (c < 6) {
      const int cc = c + 2;
      const int rb = (cc < 4) ? ibase_s[e] : jbase_s[e];
      const float* p = emb + (size_t)rb * EMBED + (cc & 3) * 64 + sq * 8;
      gh0 = *(const float4*)(p);
      gh1 = *(const float4*)(p + 4);
    }
    __builtin_amdgcn_sched_barrier(0);

    // raw barrier: drain LDS writes only -- NO vmcnt(0) drain
    asm volatile("s_waitcnt lgkmcnt(0)" ::: "memory");
    __builtin_amdgcn_s_barrier();
    asm volatile("" ::: "memory");
  }

  // ---- epilogue: dist col + bias + relu + in-lane W2 dot over wave's n ----
  const float d0 = dist_s[ln31];
  const float d1 = dist_s[32 + ln31];
  float ps0 = 0.f, ps1 = 0.f;
#pragma unroll
  for (int nt = 0; nt < 2; ++nt) {
#pragma unroll
    for (int r = 0; r < 16; ++r) {
      const int n = ng * 64 + nt * 32 + (r & 3) + ((r >> 2) << 3) + (kg << 2);
      const float4 ep = ep_s[n];
      float p0 = acc[0][nt][r] + ep.x + d0 * ep.y;
      float p1 = acc[1][nt][r] + ep.x + d1 * ep.y;
      ps0 += fmaxf(p0, 0.f) * ep.z;
      ps1 += fmaxf(p1, 0.f) * ep.z;
    }
  }
  ps0 += __shfl_xor(ps0, 32, 64);        // fold kg halves (rows +4)
  ps1 += __shfl_xor(ps1, 32, 64);
  if (lane < 32) {
    part_s[ng][ln31]      = ps0;
    part_s[ng][32 + ln31] = ps1;
  }
  __syncthreads();

  if (tid < BM) {
    float s = 0.f;
#pragma unroll
    for (int w = 0; w < 8; ++w) s += part_s[w][tid];
    float logit = s + b2[0] + (float)dbias[0];
    if (!valid_s[tid]) logit = -__builtin_inff();
    out[(size_t)wg * BM + tid] = logit;
  }
}

extern "C" void kernel_launch(void* const* d_in, const int* in_sizes, int n_in,
                              void* d_out, int out_size, void* d_ws, size_t ws_size,
                              hipStream_t stream) {
  const float* emb   = (const float*)d_in[0];
  const float* locs  = (const float*)d_in[1];
  const int*   edges = (const int*)d_in[2];
  const int*   dbias = (const int*)d_in[3];
  const float* W1    = (const float*)d_in[4];
  const float* b1    = (const float*)d_in[5];
  const float* W2    = (const float*)d_in[6];
  const float* b2    = (const float*)d_in[7];
  float*       out   = (float*)d_out;
  short*       W1F   = (short*)d_ws;   // 512*512*2 = 512 KiB fragment-major

  w1f_kernel<<<dim3(64), dim3(512), 0, stream>>>(W1, W1F);
  edge_kernel<<<dim3(NBLK), dim3(NTHREADS), 0, stream>>>(
      emb, locs, edges, dbias, W1, b1, W2, b2, (const short*)W1F, out);
}

// Round 7
// 163.422 us; speedup vs baseline: 2.1410x; 1.0077x over previous
//
#include <hip/hip_runtime.h>
#include <math.h>

#define EMBED    256
#define HIDDEN   512
#define KDIM     512
#define Nn       2000
#define Ee       2000
#define BM       128     // edges per block
#define NTHREADS 512     // 8 waves, each owns a 64-wide n-slice x all 128 edges
#define NBLK     2000    // 2000 * 128 = 256000 edges
#define PITCH    72      // shorts per feat row (64 + 8 pad; conflict-free b128)

typedef __attribute__((ext_vector_type(8)))  short bf16x8;
typedef __attribute__((ext_vector_type(16))) float f32x16;

static __device__ __forceinline__ short f2bf(float f) {
  unsigned u = __builtin_bit_cast(unsigned, f);
  u += 0x7fffu + ((u >> 16) & 1u);
  return (short)(u >> 16);
}

static __device__ __forceinline__ bf16x8 cvt8(float4 a, float4 b) {
  bf16x8 v;
  v[0]=f2bf(a.x); v[1]=f2bf(a.y); v[2]=f2bf(a.z); v[3]=f2bf(a.w);
  v[4]=f2bf(b.x); v[5]=f2bf(b.y); v[6]=f2bf(b.z); v[7]=f2bf(b.w);
  return v;
}

// ---- prep: W1 (513x512 f32 [k][n]) -> fragment-major W1F bf16 ----
// W1F[((tn*32 + tk)*64 + lane)*8 + q] = W1[tk*16 + (lane>>5)*8 + q][tn*32 + (lane&31)]
__global__ void w1f_kernel(const float* __restrict__ W1, short* __restrict__ W1F) {
  const int t  = blockIdx.x * 512 + threadIdx.x;   // 32768 fragment-lanes
  const int l  = t & 63;
  const int tk = (t >> 6) & 31;
  const int tn = t >> 11;
  const int n  = tn * 32 + (l & 31);
  const int k0 = tk * 16 + (l >> 5) * 8;
  bf16x8 v;
#pragma unroll
  for (int q = 0; q < 8; ++q)
    v[q] = f2bf(W1[(size_t)(k0 + q) * HIDDEN + n]);
  *(bf16x8*)(W1F + (size_t)t * 8) = v;
}

// ---- main fused kernel: 2000 blocks x 128 edges, 8 waves ----
__global__ __launch_bounds__(NTHREADS, 2)
void edge_kernel(const float* __restrict__ emb, const float* __restrict__ locs,
                 const int* __restrict__ edges, const int* __restrict__ dbias,
                 const float* __restrict__ W1, const float* __restrict__ b1,
                 const float* __restrict__ W2, const float* __restrict__ b2,
                 const short* __restrict__ W1F, float* __restrict__ out)
{
  __shared__ short  feat[2][BM][PITCH];   // 36,864 B (dbuf 64-K chunks)
  __shared__ float4 ep_s[HIDDEN];         //  8,192 B {b1, W1[512][n], W2, 0}
  __shared__ float  part_s[8][BM];        //  4,096 B
  __shared__ float  dist_s[BM];
  __shared__ int    valid_s[BM];
  __shared__ int    ibase_s[BM];
  __shared__ int    jbase_s[BM];          // total ~51.2 KB

  const int tid = threadIdx.x;

  // bijective XCD-chunked swizzle: 2000 = 8 * 250
  const int wg = (blockIdx.x & 7) * (NBLK / 8) + (blockIdx.x >> 3);

  // ---- meta + epilogue tables ----
  if (tid < BM) {
    const int g  = wg * BM + tid;
    const int b  = g / Ee;
    const int i0 = edges[2 * g];
    const int j0 = edges[2 * g + 1];
    valid_s[tid] = (i0 >= 0) && (j0 >= 0);
    const int ib = b * Nn + (i0 < 0 ? 0 : i0);
    const int jb = b * Nn + (j0 < 0 ? 0 : j0);
    ibase_s[tid] = ib;
    jbase_s[tid] = jb;
    const float dx = locs[2 * (size_t)ib]     - locs[2 * (size_t)jb];
    const float dy = locs[2 * (size_t)ib + 1] - locs[2 * (size_t)jb + 1];
    dist_s[tid] = sqrtf(dx * dx + dy * dy);
  }
  ep_s[tid] = make_float4(b1[tid], W1[(size_t)KDIM * HIDDEN + tid], W2[tid], 0.f);
  asm volatile("s_waitcnt lgkmcnt(0)" ::: "memory");
  __builtin_amdgcn_s_barrier();
  asm volatile("" ::: "memory");

  // staging: 4 threads per edge, 64 B (16 floats) per chunk
  const int e  = tid >> 2;     // edge 0..127
  const int sq = tid & 3;

  const int lane = tid & 63;
  const int ng   = tid >> 6;   // wave id 0..7 -> n-slice [ng*64, +64)
  const int ln31 = lane & 31;
  const int kg   = lane >> 5;

  // ---- prologue: stage chunk 0, load wa(0), issue gather(1) last ----
  {
    const float* p = emb + (size_t)ibase_s[e] * EMBED + sq * 16;
    float4 v0 = *(const float4*)(p);
    float4 v1 = *(const float4*)(p + 4);
    float4 v2 = *(const float4*)(p + 8);
    float4 v3 = *(const float4*)(p + 12);
    *(bf16x8*)&feat[0][e][sq * 16]     = cvt8(v0, v1);
    *(bf16x8*)&feat[0][e][sq * 16 + 8] = cvt8(v2, v3);
  }
  bf16x8 wc0[4], wc1[4];
  {
    const short* wb = W1F + (size_t)(ng * 64) * 512 + lane * 8;
#pragma unroll
    for (int ks = 0; ks < 4; ++ks) {
      wc0[ks] = *(const bf16x8*)(wb + ks * 512);
      wc1[ks] = *(const bf16x8*)(wb + 32 * 512 + ks * 512);
    }
  }
  float4 g0, g1, g2, g3;
  {
    const float* p = emb + (size_t)ibase_s[e] * EMBED + 64 + sq * 16;
    g0 = *(const float4*)(p);
    g1 = *(const float4*)(p + 4);
    g2 = *(const float4*)(p + 8);
    g3 = *(const float4*)(p + 12);
  }
  asm volatile("s_waitcnt lgkmcnt(0)" ::: "memory");
  __builtin_amdgcn_s_barrier();
  asm volatile("" ::: "memory");

  f32x16 acc[4][2];            // [edge-tile et 0..3][n-tile nt 0..1]
#pragma unroll
  for (int et = 0; et < 4; ++et)
#pragma unroll
    for (int nt = 0; nt < 2; ++nt)
#pragma unroll
      for (int q = 0; q < 16; ++q) acc[et][nt][q] = 0.f;

  // ---- K loop: 8 chunks of 64 ----
#pragma unroll 1
  for (int c = 0; c < 8; ++c) {
    const int bb = c & 1;
    const int nbuf = bb ^ 1;

    // prefetch next chunk's wa fragments (reg double-buffer)
    bf16x8 wn0[4], wn1[4];
    if (c < 7) {
      const short* wb = W1F + (size_t)(ng * 64 + (c + 1) * 4) * 512 + lane * 8;
#pragma unroll
      for (int ks = 0; ks < 4; ++ks) {
        wn0[ks] = *(const bf16x8*)(wb + ks * 512);
        wn1[ks] = *(const bf16x8*)(wb + 32 * 512 + ks * 512);
      }
    }

    // MFMA on current buffer with current wa regs
#pragma unroll
    for (int ks = 0; ks < 4; ++ks) {
#pragma unroll
      for (int et = 0; et < 4; ++et) {
        bf16x8 fb = *(const bf16x8*)(&feat[bb][et * 32 + ln31][ks * 16 + kg * 8]);
        acc[et][0] = __builtin_amdgcn_mfma_f32_32x32x16_bf16(wc0[ks], fb, acc[et][0], 0, 0, 0);
        acc[et][1] = __builtin_amdgcn_mfma_f32_32x32x16_bf16(wc1[ks], fb, acc[et][1], 0, 0, 0);
      }
    }

    // land held gather (chunk c+1) into next buffer (ds_write; lgkm only)
    if (c < 7) {
      *(bf16x8*)&feat[nbuf][e][sq * 16]     = cvt8(g0, g1);
      *(bf16x8*)&feat[nbuf][e][sq * 16 + 8] = cvt8(g2, g3);
    }

    // issue gather for chunk c+2 LAST (newest vmem; counted waits spare it)
    __builtin_amdgcn_sched_barrier(0);
    if (c < 6) {
      const int cc = c + 2;
      const int rb = (cc < 4) ? ibase_s[e] : jbase_s[e];
      const float* p = emb + (size_t)rb * EMBED + (cc & 3) * 64 + sq * 16;
      g0 = *(const float4*)(p);
      g1 = *(const float4*)(p + 4);
      g2 = *(const float4*)(p + 8);
      g3 = *(const float4*)(p + 12);
    }
    __builtin_amdgcn_sched_barrier(0);

    // raw barrier: drain LDS writes only -- NO vmcnt(0) drain
    asm volatile("s_waitcnt lgkmcnt(0)" ::: "memory");
    __builtin_amdgcn_s_barrier();
    asm volatile("" ::: "memory");

#pragma unroll
    for (int ks = 0; ks < 4; ++ks) { wc0[ks] = wn0[ks]; wc1[ks] = wn1[ks]; }
  }

  // ---- epilogue: dist col + bias + relu + in-lane W2 dot over wave's n ----
  float dv[4], ps[4];
#pragma unroll
  for (int et = 0; et < 4; ++et) {
    dv[et] = dist_s[et * 32 + ln31];
    ps[et] = 0.f;
  }
#pragma unroll
  for (int nt = 0; nt < 2; ++nt) {
#pragma unroll
    for (int r = 0; r < 16; ++r) {
      const int n = ng * 64 + nt * 32 + (r & 3) + ((r >> 2) << 3) + (kg << 2);
      const float4 ep = ep_s[n];
#pragma unroll
      for (int et = 0; et < 4; ++et) {
        float p = acc[et][nt][r] + ep.x + dv[et] * ep.y;
        ps[et] += fmaxf(p, 0.f) * ep.z;
      }
    }
  }
#pragma unroll
  for (int et = 0; et < 4; ++et) ps[et] += __shfl_xor(ps[et], 32, 64);
  if (lane < 32) {
#pragma unroll
    for (int et = 0; et < 4; ++et) part_s[ng][et * 32 + ln31] = ps[et];
  }
  __syncthreads();

  if (tid < BM) {
    float s = 0.f;
#pragma unroll
    for (int w = 0; w < 8; ++w) s += part_s[w][tid];
    float logit = s + b2[0] + (float)dbias[0];
    if (!valid_s[tid]) logit = -__builtin_inff();
    out[(size_t)wg * BM + tid] = logit;
  }
}

extern "C" void kernel_launch(void* const* d_in, const int* in_sizes, int n_in,
                              void* d_out, int out_size, void* d_ws, size_t ws_size,
                              hipStream_t stream) {
  const float* emb   = (const float*)d_in[0];
  const float* locs  = (const float*)d_in[1];
  const int*   edges = (const int*)d_in[2];
  const int*   dbias = (const int*)d_in[3];
  const float* W1    = (const float*)d_in[4];
  const float* b1    = (const float*)d_in[5];
  const float* W2    = (const float*)d_in[6];
  const float* b2    = (const float*)d_in[7];
  float*       out   = (float*)d_out;
  short*       W1F   = (short*)d_ws;   // 512*512*2 = 512 KiB fragment-major

  w1f_kernel<<<dim3(64), dim3(512), 0, stream>>>(W1, W1F);
  edge_kernel<<<dim3(NBLK), dim3(NTHREADS), 0, stream>>>(
      emb, locs, edges, dbias, W1, b1, W2, b2, (const short*)W1F, out);
}